// Round 1
// baseline (2460.974 us; speedup 1.0000x reference)
//
#include <hip/hip_runtime.h>

// ---------------------------------------------------------------------------
// FC (GCN drug/protein + MLP head) — f32, aggregate-before-matmul restructure.
// out = concat(y[4096], feature[4096*512]) f32.
// ---------------------------------------------------------------------------

#define EPSV 1e-5f
#define LEAKYV 0.01f
#define RRELUV 0.22916666666666666f  // (1/8 + 1/3)/2

// ---------------- tiny utility kernels ----------------
__global__ void fill_f32_k(float* __restrict__ p, float v, int n) {
  int i = blockIdx.x * blockDim.x + threadIdx.x;
  int st = gridDim.x * blockDim.x;
  for (; i < n; i += st) p[i] = v;
}
__global__ void fill_i32_k(int* __restrict__ p, int v, int n) {
  int i = blockIdx.x * blockDim.x + threadIdx.x;
  int st = gridDim.x * blockDim.x;
  for (; i < n; i += st) p[i] = v;
}
__global__ void deg_accum_k(const int* __restrict__ dst, const float* __restrict__ w,
                            float* __restrict__ deg, int E) {
  int i = blockIdx.x * blockDim.x + threadIdx.x;
  int st = gridDim.x * blockDim.x;
  for (; i < E; i += st) atomicAdd(&deg[dst[i]], w[i]);
}
__global__ void dinv_k(float* __restrict__ deg, int n) {  // deg >= 2 always (self-loop w=2)
  int i = blockIdx.x * blockDim.x + threadIdx.x;
  int st = gridDim.x * blockDim.x;
  for (; i < n; i += st) deg[i] = 1.0f / sqrtf(deg[i]);
}
__global__ void slot_k(const int* __restrict__ idx, int* __restrict__ slot, int B) {
  int i = blockIdx.x * blockDim.x + threadIdx.x;
  if (i < B) atomicCAS(&slot[idx[i]], -1, i);  // winner batch-row owns the node
}
__global__ void count_k(const int* __restrict__ dst, const int* __restrict__ slot,
                        int* __restrict__ cnt, int E) {
  int i = blockIdx.x * blockDim.x + threadIdx.x;
  int st = gridDim.x * blockDim.x;
  for (; i < E; i += st) { int d = dst[i]; if (slot[d] >= 0) atomicAdd(&cnt[d], 1); }
}
__global__ void alloc_k(const int* __restrict__ cnt, int* __restrict__ rowstart,
                        int* __restrict__ total, int n) {
  int i = blockIdx.x * blockDim.x + threadIdx.x;
  int st = gridDim.x * blockDim.x;
  for (; i < n; i += st) { int c = cnt[i]; if (c > 0) rowstart[i] = atomicAdd(total, c); }
}
__global__ void fill_edges_k(const int* __restrict__ dst, const int* __restrict__ slot,
                             const int* __restrict__ rowstart, int* __restrict__ fil,
                             int* __restrict__ elist, int E) {
  int i = blockIdx.x * blockDim.x + threadIdx.x;
  int st = gridDim.x * blockDim.x;
  for (; i < E; i += st) {
    int d = dst[i];
    if (slot[d] >= 0) { int p = rowstart[d] + atomicAdd(&fil[d], 1); elist[p] = i; }
  }
}
__global__ void rowmap_k(const int* __restrict__ idx, const int* __restrict__ slot,
                         int* __restrict__ rmap, int B) {
  int i = blockIdx.x * blockDim.x + threadIdx.x;
  if (i < B) rmap[i] = slot[idx[i]];
}

// ---------------- GCN input-space aggregation ----------------
// block i: if batch row i is the winner for its node, compute
// agg[i] = 2*dinv[n]^2 * x[n] + sum_e( w_e * dinv[src_e] * dinv[n] * x[src_e] )
template <int ROWLEN>  // floats per row, multiple of 4
__global__ __launch_bounds__(256) void gcn_agg_k(
    const float* __restrict__ x, const int* __restrict__ bidx,
    const int* __restrict__ slot, const float* __restrict__ dinv,
    const int* __restrict__ esrc, const float* __restrict__ ew,
    const int* __restrict__ elist, const int* __restrict__ rowstart,
    const int* __restrict__ cnt, float* __restrict__ agg) {
  constexpr int NV4 = ROWLEN / 4;
  constexpr int NCH = (NV4 + 255) / 256;
  int i = blockIdx.x;
  int node = bidx[i];
  if (slot[node] != i) return;  // duplicates / losers exit
  float dn = dinv[node];
  int t = threadIdx.x;
  float4 acc[NCH];
  {
    const float4* xr = (const float4*)(x + (size_t)node * ROWLEN);
    float cs = 2.0f * dn * dn;
#pragma unroll
    for (int ch = 0; ch < NCH; ++ch) {
      int c = t + ch * 256;
      if ((NV4 & 255) == 0 || c < NV4) {
        float4 v = xr[c];
        acc[ch].x = cs * v.x; acc[ch].y = cs * v.y;
        acc[ch].z = cs * v.z; acc[ch].w = cs * v.w;
      }
    }
  }
  int start = rowstart[node];
  int n = cnt[node];
  int j = 0;
  for (; j + 2 <= n; j += 2) {  // 2-way unroll: two row-gathers in flight
    int e0 = elist[start + j], e1 = elist[start + j + 1];
    int s0 = esrc[e0], s1 = esrc[e1];
    float c0 = ew[e0] * dinv[s0] * dn;
    float c1 = ew[e1] * dinv[s1] * dn;
    const float4* r0 = (const float4*)(x + (size_t)s0 * ROWLEN);
    const float4* r1 = (const float4*)(x + (size_t)s1 * ROWLEN);
#pragma unroll
    for (int ch = 0; ch < NCH; ++ch) {
      int c = t + ch * 256;
      if ((NV4 & 255) == 0 || c < NV4) {
        float4 v0 = r0[c], v1 = r1[c];
        acc[ch].x += c0 * v0.x + c1 * v1.x;
        acc[ch].y += c0 * v0.y + c1 * v1.y;
        acc[ch].z += c0 * v0.z + c1 * v1.z;
        acc[ch].w += c0 * v0.w + c1 * v1.w;
      }
    }
  }
  if (j < n) {
    int e0 = elist[start + j];
    int s0 = esrc[e0];
    float c0 = ew[e0] * dinv[s0] * dn;
    const float4* r0 = (const float4*)(x + (size_t)s0 * ROWLEN);
#pragma unroll
    for (int ch = 0; ch < NCH; ++ch) {
      int c = t + ch * 256;
      if ((NV4 & 255) == 0 || c < NV4) {
        float4 v0 = r0[c];
        acc[ch].x += c0 * v0.x; acc[ch].y += c0 * v0.y;
        acc[ch].z += c0 * v0.z; acc[ch].w += c0 * v0.w;
      }
    }
  }
  float4* out = (float4*)(agg + (size_t)i * ROWLEN);
#pragma unroll
  for (int ch = 0; ch < NCH; ++ch) {
    int c = t + ch * 256;
    if ((NV4 & 255) == 0 || c < NV4) out[c] = acc[ch];
  }
}

// ---------------- fused SGEMM ----------------
// C[M,N] = epi(A'[M,K] @ B[K,N]); A' selected by ASRC:
//   0: A rows direct   1: A rows via rowmap   2: concat(d_vecs|p_emb|ecf_b|gos_b)
// EPI: 0: leaky(x+bias)  1: leaky(bn(x+bias))  2: bn(rrelu(x+bias))
template <int BM, int BN, int ASRC, int EPI>
__global__ __launch_bounds__(256) void sgemm_k(
    const float* __restrict__ A, int lda, const float* __restrict__ Bm,
    float* __restrict__ C, int ldc, int M, int N, int K,
    const int* __restrict__ rowmap,
    const float* __restrict__ S0, const float* __restrict__ S1,
    const float* __restrict__ S2, const float* __restrict__ S3,
    const float* __restrict__ bias, const float* __restrict__ gam,
    const float* __restrict__ bet, const float* __restrict__ mu,
    const float* __restrict__ var) {
  constexpr int BK = 16;
  constexpr int FM = BM / 64, FN = BN / 64;
  __shared__ float As[BK][BM];
  __shared__ float Bs[BK][BN];
  int t = threadIdx.x;
  int tx = t & 15, ty = t >> 4;
  int bm = blockIdx.y, bn = blockIdx.x;

  float acc[FM * 4][FN * 4];
#pragma unroll
  for (int i = 0; i < FM * 4; ++i)
#pragma unroll
    for (int j = 0; j < FN * 4; ++j) acc[i][j] = 0.f;

  int arow[FM];
#pragma unroll
  for (int l = 0; l < FM; ++l) {
    int q = t + l * 256;
    int rg = bm * BM + (q >> 2);
    if constexpr (ASRC == 1) arow[l] = rowmap[rg];
    else arow[l] = rg;
  }

  int nk = (K + BK - 1) / BK;
  for (int kt = 0; kt < nk; ++kt) {
    int k0 = kt * BK;
#pragma unroll
    for (int l = 0; l < FM; ++l) {
      int q = t + l * 256;
      int row = q >> 2, kq = q & 3;
      int kcol = k0 + kq * 4;
      float4 v = {0.f, 0.f, 0.f, 0.f};
      if (kcol < K) {
        if constexpr (ASRC != 2) {
          v = *(const float4*)&A[(size_t)arow[l] * lda + kcol];
        } else {
          int rg = arow[l];
          const float* p;
          if (kcol < 300)       p = S0 + (size_t)rg * 300 + kcol;
          else if (kcol < 1324) p = S1 + (size_t)rg * 1024 + (kcol - 300);
          else if (kcol < 2348) p = S2 + (size_t)rg * 1024 + (kcol - 1324);
          else                  p = S3 + (size_t)rg * 1024 + (kcol - 2348);
          v = *(const float4*)p;
        }
      }
      As[(kq << 2) + 0][row] = v.x; As[(kq << 2) + 1][row] = v.y;
      As[(kq << 2) + 2][row] = v.z; As[(kq << 2) + 3][row] = v.w;
    }
#pragma unroll
    for (int l = 0; l < FN; ++l) {
      int q = t + l * 256;
      int krow = q / (BN / 4), c4 = q % (BN / 4);
      int kg = k0 + krow;
      float4 v = {0.f, 0.f, 0.f, 0.f};
      if (kg < K) v = *(const float4*)&Bm[(size_t)kg * N + bn * BN + (c4 << 2)];
      *(float4*)&Bs[krow][c4 << 2] = v;
    }
    __syncthreads();
#pragma unroll
    for (int kk = 0; kk < BK; ++kk) {
      float av[FM * 4], bv[FN * 4];
#pragma unroll
      for (int fm = 0; fm < FM; ++fm) {
        float4 tmp = *(const float4*)&As[kk][fm * 64 + ty * 4];
        av[fm * 4 + 0] = tmp.x; av[fm * 4 + 1] = tmp.y;
        av[fm * 4 + 2] = tmp.z; av[fm * 4 + 3] = tmp.w;
      }
#pragma unroll
      for (int fn = 0; fn < FN; ++fn) {
        float4 tmp = *(const float4*)&Bs[kk][fn * 64 + tx * 4];
        bv[fn * 4 + 0] = tmp.x; bv[fn * 4 + 1] = tmp.y;
        bv[fn * 4 + 2] = tmp.z; bv[fn * 4 + 3] = tmp.w;
      }
#pragma unroll
      for (int i = 0; i < FM * 4; ++i)
#pragma unroll
        for (int j = 0; j < FN * 4; ++j) acc[i][j] = fmaf(av[i], bv[j], acc[i][j]);
    }
    __syncthreads();
  }

#pragma unroll
  for (int fm = 0; fm < FM; ++fm)
#pragma unroll
    for (int i = 0; i < 4; ++i) {
      int r = bm * BM + fm * 64 + ty * 4 + i;
#pragma unroll
      for (int fn = 0; fn < FN; ++fn) {
        int cb = bn * BN + fn * 64 + tx * 4;
        float4 o;
        float* ov = (float*)&o;
#pragma unroll
        for (int j = 0; j < 4; ++j) {
          int c = cb + j;
          float v = acc[fm * 4 + i][fn * 4 + j] + bias[c];
          if constexpr (EPI == 0) {
            v = v > 0.f ? v : LEAKYV * v;
          } else if constexpr (EPI == 1) {
            v = (v - mu[c]) * (1.0f / sqrtf(var[c] + EPSV)) * gam[c] + bet[c];
            v = v > 0.f ? v : LEAKYV * v;
          } else {
            v = v > 0.f ? v : RRELUV * v;
            v = (v - mu[c]) * (1.0f / sqrtf(var[c] + EPSV)) * gam[c] + bet[c];
          }
          ov[j] = v;
        }
        *(float4*)&C[(size_t)r * ldc + cb] = o;
      }
    }
}

// ---------------- final y = o @ W4 + b4 ----------------
__global__ __launch_bounds__(256) void out_y_k(const float* __restrict__ o,
                                               const float* __restrict__ W4,
                                               const float* __restrict__ b4,
                                               float* __restrict__ y, int B) {
  int w = (blockIdx.x * blockDim.x + threadIdx.x) >> 6;
  int lane = threadIdx.x & 63;
  if (w >= B) return;
  float v = o[(size_t)w * 128 + lane] * W4[lane] +
            o[(size_t)w * 128 + 64 + lane] * W4[64 + lane];
  v += __shfl_down(v, 32, 64);
  v += __shfl_down(v, 16, 64);
  v += __shfl_down(v, 8, 64);
  v += __shfl_down(v, 4, 64);
  v += __shfl_down(v, 2, 64);
  v += __shfl_down(v, 1, 64);
  if (lane == 0) y[w] = v + b4[0];
}

// ---------------------------------------------------------------------------
static inline int nblk(long long n, int t) {
  long long b = (n + t - 1) / t;
  if (b > 2048) b = 2048;
  return (int)b;
}

extern "C" void kernel_launch(void* const* d_in, const int* in_sizes, int n_in,
                              void* d_out, int out_size, void* d_ws, size_t ws_size,
                              hipStream_t stream) {
  const int*   d_index = (const int*)d_in[0];
  const int*   p_index = (const int*)d_in[1];
  const float* d_vecs  = (const float*)d_in[2];
  const float* p_emb   = (const float*)d_in[3];
  const float* d_ecfps = (const float*)d_in[4];
  const int*   d_eidx  = (const int*)d_in[5];
  const float* d_ew    = (const float*)d_in[6];
  const float* p_gos   = (const float*)d_in[7];
  const int*   p_eidx  = (const int*)d_in[8];
  const float* p_ew    = (const float*)d_in[9];
  const float* Wd = (const float*)d_in[10]; const float* bd = (const float*)d_in[11];
  const float* Wp = (const float*)d_in[12]; const float* bp = (const float*)d_in[13];
  const float* W1 = (const float*)d_in[14]; const float* b1 = (const float*)d_in[15];
  const float* g1 = (const float*)d_in[16]; const float* be1 = (const float*)d_in[17];
  const float* m1 = (const float*)d_in[18]; const float* v1 = (const float*)d_in[19];
  const float* W2 = (const float*)d_in[20]; const float* b2 = (const float*)d_in[21];
  const float* g2 = (const float*)d_in[22]; const float* be2 = (const float*)d_in[23];
  const float* m2 = (const float*)d_in[24]; const float* v2 = (const float*)d_in[25];
  const float* W3 = (const float*)d_in[26]; const float* b3 = (const float*)d_in[27];
  const float* g3 = (const float*)d_in[28]; const float* be3 = (const float*)d_in[29];
  const float* m3 = (const float*)d_in[30]; const float* v3 = (const float*)d_in[31];
  const float* W4 = (const float*)d_in[32]; const float* b4 = (const float*)d_in[33];

  const int B  = in_sizes[0];
  const int ND = in_sizes[4] / 1024;
  const int NP = in_sizes[7] / 2812;
  const int ED = in_sizes[5] / 2;
  const int EP = in_sizes[8] / 2;

  // ---- workspace carve-up (256B aligned) ----
  char* w = (char*)d_ws;
  auto carve = [&](size_t bytes) {
    char* p = w;
    w += (bytes + 255) & ~(size_t)255;
    return p;
  };
  float* deg_d = (float*)carve((size_t)ND * 4);
  float* deg_p = (float*)carve((size_t)NP * 4);
  int* slot_d = (int*)carve((size_t)ND * 4);
  int* slot_p = (int*)carve((size_t)NP * 4);
  int* cnt_d  = (int*)carve((size_t)ND * 4);
  int* cnt_p  = (int*)carve((size_t)NP * 4);
  int* fil_d  = (int*)carve((size_t)ND * 4);
  int* fil_p  = (int*)carve((size_t)NP * 4);
  int* totals = (int*)carve(256);
  int* rs_d   = (int*)carve((size_t)ND * 4);
  int* rs_p   = (int*)carve((size_t)NP * 4);
  int* rmap_d = (int*)carve((size_t)B * 4);
  int* rmap_p = (int*)carve((size_t)B * 4);
  int* elist_d = (int*)carve((size_t)ED * 4);
  int* elist_p = (int*)carve((size_t)EP * 4);
  float* agg_d = (float*)carve((size_t)B * 1024 * 4);
  float* agg_p = (float*)carve((size_t)B * 2812 * 4);
  float* ecf_b = (float*)carve((size_t)B * 1024 * 4);
  float* gos_b = (float*)carve((size_t)B * 1024 * 4);
  float* h1    = (float*)carve((size_t)B * 1024 * 4);
  float* o3    = (float*)carve((size_t)B * 128 * 4);
  (void)ws_size; (void)n_in; (void)out_size;

  float* y_out   = (float*)d_out;
  float* feature = (float*)d_out + B;  // [B,512]

  // ---- init (contiguous regions: deg_*=2.0, slot_*=-1, counters=0) ----
  int n_deg  = (int)(((char*)slot_d - (char*)deg_d) / 4);
  int n_slot = (int)(((char*)cnt_d - (char*)slot_d) / 4);
  int n_zero = (int)(((char*)rs_d - (char*)cnt_d) / 4);
  fill_f32_k<<<nblk(n_deg, 256), 256, 0, stream>>>(deg_d, 2.0f, n_deg);
  fill_i32_k<<<nblk(n_slot, 256), 256, 0, stream>>>(slot_d, -1, n_slot);
  fill_i32_k<<<nblk(n_zero, 256), 256, 0, stream>>>(cnt_d, 0, n_zero);

  // ---- degrees -> dinv ----
  deg_accum_k<<<nblk(ED, 256), 256, 0, stream>>>(d_eidx + ED, d_ew, deg_d, ED);
  deg_accum_k<<<nblk(EP, 256), 256, 0, stream>>>(p_eidx + EP, p_ew, deg_p, EP);
  dinv_k<<<nblk(ND, 256), 256, 0, stream>>>(deg_d, ND);
  dinv_k<<<nblk(NP, 256), 256, 0, stream>>>(deg_p, NP);

  // ---- needed-node slots, compact per-dst edge lists ----
  slot_k<<<(B + 255) / 256, 256, 0, stream>>>(d_index, slot_d, B);
  slot_k<<<(B + 255) / 256, 256, 0, stream>>>(p_index, slot_p, B);
  count_k<<<nblk(ED, 256), 256, 0, stream>>>(d_eidx + ED, slot_d, cnt_d, ED);
  count_k<<<nblk(EP, 256), 256, 0, stream>>>(p_eidx + EP, slot_p, cnt_p, EP);
  alloc_k<<<nblk(ND, 256), 256, 0, stream>>>(cnt_d, rs_d, totals + 0, ND);
  alloc_k<<<nblk(NP, 256), 256, 0, stream>>>(cnt_p, rs_p, totals + 1, NP);
  fill_edges_k<<<nblk(ED, 256), 256, 0, stream>>>(d_eidx + ED, slot_d, rs_d, fil_d, elist_d, ED);
  fill_edges_k<<<nblk(EP, 256), 256, 0, stream>>>(p_eidx + EP, slot_p, rs_p, fil_p, elist_p, EP);
  rowmap_k<<<(B + 255) / 256, 256, 0, stream>>>(d_index, slot_d, rmap_d, B);
  rowmap_k<<<(B + 255) / 256, 256, 0, stream>>>(p_index, slot_p, rmap_p, B);

  // ---- input-space aggregation (needed rows only) ----
  gcn_agg_k<1024><<<B, 256, 0, stream>>>(d_ecfps, d_index, slot_d, deg_d,
                                         d_eidx, d_ew, elist_d, rs_d, cnt_d, agg_d);
  gcn_agg_k<2812><<<B, 256, 0, stream>>>(p_gos, p_index, slot_p, deg_p,
                                         p_eidx, p_ew, elist_p, rs_p, cnt_p, agg_p);

  // ---- GEMM stack ----
  // G1: ecf_b = leaky(agg_d[rowmap] @ Wd + bd)   [4096,1024]
  sgemm_k<128, 128, 1, 0><<<dim3(1024 / 128, 4096 / 128), 256, 0, stream>>>(
      agg_d, 1024, Wd, ecf_b, 1024, B, 1024, 1024, rmap_d,
      nullptr, nullptr, nullptr, nullptr, bd, nullptr, nullptr, nullptr, nullptr);
  // G2: gos_b = leaky(agg_p[rowmap] @ Wp + bp)   [4096,1024]
  sgemm_k<128, 128, 1, 0><<<dim3(1024 / 128, 4096 / 128), 256, 0, stream>>>(
      agg_p, 2812, Wp, gos_b, 1024, B, 1024, 2812, rmap_p,
      nullptr, nullptr, nullptr, nullptr, bp, nullptr, nullptr, nullptr, nullptr);
  // G3: h1 = leaky(bn1(concat @ W1 + b1))        [4096,1024], K=3372
  sgemm_k<128, 128, 2, 1><<<dim3(1024 / 128, 4096 / 128), 256, 0, stream>>>(
      nullptr, 0, W1, h1, 1024, B, 1024, 3372, nullptr,
      d_vecs, p_emb, ecf_b, gos_b, b1, g1, be1, m1, v1);
  // G4: feature = leaky(bn2(h1 @ W2 + b2))       [4096,512] -> d_out
  sgemm_k<64, 64, 0, 1><<<dim3(512 / 64, 4096 / 64), 256, 0, stream>>>(
      h1, 1024, W2, feature, 512, B, 512, 1024, nullptr,
      nullptr, nullptr, nullptr, nullptr, b2, g2, be2, m2, v2);
  // G5: o3 = bn3(rrelu(feature @ W3 + b3))       [4096,128]
  sgemm_k<64, 64, 0, 2><<<dim3(128 / 64, 4096 / 64), 256, 0, stream>>>(
      feature, 512, W3, o3, 128, B, 128, 512, nullptr,
      nullptr, nullptr, nullptr, nullptr, b3, g3, be3, m3, v3);
  // y = o3 @ W4 + b4
  out_y_k<<<(B * 64 + 255) / 256, 256, 0, stream>>>(o3, W4, b4, y_out, B);
}

// Round 2
// 1417.185 us; speedup vs baseline: 1.7365x; 1.7365x over previous
//
#include <hip/hip_runtime.h>

// ---------------------------------------------------------------------------
// FC — GCN aggregate-before-matmul + split-bf16 MFMA GEMM stack.
// out = concat(y[4096], feature[4096*512]) f32.
// ---------------------------------------------------------------------------

#define EPSV 1e-5f
#define LEAKYV 0.01f
#define RRELUV 0.22916666666666666f  // (1/8 + 1/3)/2

typedef __bf16 bf16x8 __attribute__((ext_vector_type(8)));
typedef float f32x4 __attribute__((ext_vector_type(4)));
typedef unsigned short u16x4 __attribute__((ext_vector_type(4)));

__device__ __forceinline__ unsigned short f2bf(float x) {  // RNE truncate to bf16
  unsigned u = __builtin_bit_cast(unsigned, x);
  u = (u + 0x7FFFu + ((u >> 16) & 1u)) >> 16;
  return (unsigned short)u;
}
__device__ __forceinline__ float bf2f(unsigned short h) {
  unsigned u = ((unsigned)h) << 16;
  return __builtin_bit_cast(float, u);
}

// ---------------- tiny utility kernels ----------------
__global__ void fill_f32_k(float* __restrict__ p, float v, int n) {
  int i = blockIdx.x * blockDim.x + threadIdx.x;
  int st = gridDim.x * blockDim.x;
  for (; i < n; i += st) p[i] = v;
}
__global__ void fill_i32_k(int* __restrict__ p, int v, int n) {
  int i = blockIdx.x * blockDim.x + threadIdx.x;
  int st = gridDim.x * blockDim.x;
  for (; i < n; i += st) p[i] = v;
}
__global__ void deg_accum_k(const int* __restrict__ dst, const float* __restrict__ w,
                            float* __restrict__ deg, int E) {
  int i = blockIdx.x * blockDim.x + threadIdx.x;
  int st = gridDim.x * blockDim.x;
  for (; i < E; i += st) atomicAdd(&deg[dst[i]], w[i]);
}
__global__ void dinv_k(float* __restrict__ deg, int n) {
  int i = blockIdx.x * blockDim.x + threadIdx.x;
  int st = gridDim.x * blockDim.x;
  for (; i < n; i += st) deg[i] = 1.0f / sqrtf(deg[i]);
}
__global__ void slot_k(const int* __restrict__ idx, int* __restrict__ slot, int B) {
  int i = blockIdx.x * blockDim.x + threadIdx.x;
  if (i < B) atomicCAS(&slot[idx[i]], -1, i);
}
__global__ void count_k(const int* __restrict__ dst, const int* __restrict__ slot,
                        int* __restrict__ cnt, int E) {
  int i = blockIdx.x * blockDim.x + threadIdx.x;
  int st = gridDim.x * blockDim.x;
  for (; i < E; i += st) { int d = dst[i]; if (slot[d] >= 0) atomicAdd(&cnt[d], 1); }
}
__global__ void alloc_k(const int* __restrict__ cnt, int* __restrict__ rowstart,
                        int* __restrict__ total, int n) {
  int i = blockIdx.x * blockDim.x + threadIdx.x;
  int st = gridDim.x * blockDim.x;
  for (; i < n; i += st) { int c = cnt[i]; if (c > 0) rowstart[i] = atomicAdd(total, c); }
}
__global__ void fill_edges_k(const int* __restrict__ dst, const int* __restrict__ slot,
                             const int* __restrict__ rowstart, int* __restrict__ fil,
                             int* __restrict__ elist, int E) {
  int i = blockIdx.x * blockDim.x + threadIdx.x;
  int st = gridDim.x * blockDim.x;
  for (; i < E; i += st) {
    int d = dst[i];
    if (slot[d] >= 0) { int p = rowstart[d] + atomicAdd(&fil[d], 1); elist[p] = i; }
  }
}
__global__ void rowmap_k(const int* __restrict__ idx, const int* __restrict__ slot,
                         int* __restrict__ rmap, int B) {
  int i = blockIdx.x * blockDim.x + threadIdx.x;
  if (i < B) rmap[i] = slot[idx[i]];
}

// ---------------- GCN input-space aggregation ----------------
template <int ROWLEN>
__global__ __launch_bounds__(256) void gcn_agg_k(
    const float* __restrict__ x, const int* __restrict__ bidx,
    const int* __restrict__ slot, const float* __restrict__ dinv,
    const int* __restrict__ esrc, const float* __restrict__ ew,
    const int* __restrict__ elist, const int* __restrict__ rowstart,
    const int* __restrict__ cnt, float* __restrict__ agg) {
  constexpr int NV4 = ROWLEN / 4;
  constexpr int NCH = (NV4 + 255) / 256;
  int i = blockIdx.x;
  int node = bidx[i];
  if (slot[node] != i) return;
  float dn = dinv[node];
  int t = threadIdx.x;
  float4 acc[NCH];
  {
    const float4* xr = (const float4*)(x + (size_t)node * ROWLEN);
    float cs = 2.0f * dn * dn;
#pragma unroll
    for (int ch = 0; ch < NCH; ++ch) {
      int c = t + ch * 256;
      if ((NV4 & 255) == 0 || c < NV4) {
        float4 v = xr[c];
        acc[ch].x = cs * v.x; acc[ch].y = cs * v.y;
        acc[ch].z = cs * v.z; acc[ch].w = cs * v.w;
      }
    }
  }
  int start = rowstart[node];
  int n = cnt[node];
  int j = 0;
  for (; j + 2 <= n; j += 2) {
    int e0 = elist[start + j], e1 = elist[start + j + 1];
    int s0 = esrc[e0], s1 = esrc[e1];
    float c0 = ew[e0] * dinv[s0] * dn;
    float c1 = ew[e1] * dinv[s1] * dn;
    const float4* r0 = (const float4*)(x + (size_t)s0 * ROWLEN);
    const float4* r1 = (const float4*)(x + (size_t)s1 * ROWLEN);
#pragma unroll
    for (int ch = 0; ch < NCH; ++ch) {
      int c = t + ch * 256;
      if ((NV4 & 255) == 0 || c < NV4) {
        float4 v0 = r0[c], v1 = r1[c];
        acc[ch].x += c0 * v0.x + c1 * v1.x;
        acc[ch].y += c0 * v0.y + c1 * v1.y;
        acc[ch].z += c0 * v0.z + c1 * v1.z;
        acc[ch].w += c0 * v0.w + c1 * v1.w;
      }
    }
  }
  if (j < n) {
    int e0 = elist[start + j];
    int s0 = esrc[e0];
    float c0 = ew[e0] * dinv[s0] * dn;
    const float4* r0 = (const float4*)(x + (size_t)s0 * ROWLEN);
#pragma unroll
    for (int ch = 0; ch < NCH; ++ch) {
      int c = t + ch * 256;
      if ((NV4 & 255) == 0 || c < NV4) {
        float4 v0 = r0[c];
        acc[ch].x += c0 * v0.x; acc[ch].y += c0 * v0.y;
        acc[ch].z += c0 * v0.z; acc[ch].w += c0 * v0.w;
      }
    }
  }
  float4* out = (float4*)(agg + (size_t)i * ROWLEN);
#pragma unroll
  for (int ch = 0; ch < NCH; ++ch) {
    int c = t + ch * 256;
    if ((NV4 & 255) == 0 || c < NV4) out[c] = acc[ch];
  }
}

// ---------------- weight transpose + bf16 split ----------------
// W [K][N] f32  ->  hi/lo [N][Kpad] bf16 (zero-padded K..Kpad)
__global__ __launch_bounds__(256) void wsplit_k(const float* __restrict__ W, int K, int N,
                                                int Kpad, unsigned short* __restrict__ hi,
                                                unsigned short* __restrict__ lo) {
  __shared__ float tile[32][33];
  int tx = threadIdx.x & 31, ty = threadIdx.x >> 5;
  int n0 = blockIdx.x * 32, k0 = blockIdx.y * 32;
#pragma unroll
  for (int i = 0; i < 4; ++i) {
    int k = k0 + ty + i * 8, n = n0 + tx;
    tile[ty + i * 8][tx] = (k < K && n < N) ? W[(size_t)k * N + n] : 0.f;
  }
  __syncthreads();
#pragma unroll
  for (int i = 0; i < 4; ++i) {
    int n = n0 + ty + i * 8, k = k0 + tx;
    if (n < N) {
      float v = tile[tx][ty + i * 8];
      unsigned short h = f2bf(v);
      hi[(size_t)n * Kpad + k] = h;
      lo[(size_t)n * Kpad + k] = f2bf(v - bf2f(h));
    }
  }
}

// ---------------- split-bf16 MFMA GEMM ----------------
// C[M,N] = EPI(A'[M,K] @ B[K,N] + bias); B given pre-split/transposed [N][Kpad].
// ASRC 0: A direct  1: A rows via rowmap  2: concat(d_vecs|p_emb|ecf_b|gos_b)
// EPI  0: leaky     1: leaky(bn(.))       2: bn(rrelu(.))
template <int BM, int BN, int WM, int WN, int ASRC, int EPI>
__global__ __launch_bounds__(WM * WN * 64) void mgemm_k(
    const float* __restrict__ A, int lda,
    const unsigned short* __restrict__ Bhi, const unsigned short* __restrict__ Blo,
    int Kpad, float* __restrict__ C, int ldc, int K,
    const int* __restrict__ rowmap,
    const float* __restrict__ S0, const float* __restrict__ S1,
    const float* __restrict__ S2, const float* __restrict__ S3,
    const float* __restrict__ bias, const float* __restrict__ gam,
    const float* __restrict__ bet, const float* __restrict__ mu,
    const float* __restrict__ var) {
  constexpr int THREADS = WM * WN * 64;
  constexpr int BMW = BM / WM, BNW = BN / WN;
  constexpr int MR = BMW / 16, NR = BNW / 16;
  constexpr int AF4 = BM * 16 / THREADS;  // float4 A-chunks per thread
  constexpr int BC8 = BN * 8 / THREADS;   // 8xbf16 B-chunks per thread

  __shared__ __attribute__((aligned(16))) unsigned short sAh[BM * 64];
  __shared__ __attribute__((aligned(16))) unsigned short sAl[BM * 64];
  __shared__ __attribute__((aligned(16))) unsigned short sBh[BN * 64];
  __shared__ __attribute__((aligned(16))) unsigned short sBl[BN * 64];

  int t = threadIdx.x;
  int lane = t & 63, wid = t >> 6;
  int wm = wid / WN, wn = wid % WN;
  int bm = blockIdx.y, bn = blockIdx.x;

  int tr[AF4], ar[AF4];
#pragma unroll
  for (int l = 0; l < AF4; ++l) {
    int flat = t + l * THREADS;
    tr[l] = flat >> 4;
    int rg = bm * BM + tr[l];
    if constexpr (ASRC == 1) ar[l] = rowmap[rg];
    else ar[l] = rg;
  }

  f32x4 acc[MR][NR];
#pragma unroll
  for (int i = 0; i < MR; ++i)
#pragma unroll
    for (int j = 0; j < NR; ++j) acc[i][j] = (f32x4){0.f, 0.f, 0.f, 0.f};

  int nk = (K + 63) / 64;
  for (int kt = 0; kt < nk; ++kt) {
    int k0 = kt * 64;
    // ---- stage A: f32 -> (hi,lo) bf16, swizzled LDS ----
#pragma unroll
    for (int l = 0; l < AF4; ++l) {
      int flat = t + l * THREADS;
      int c4 = flat & 15;
      int kcol = k0 + c4 * 4;
      float vx = 0.f, vy = 0.f, vz = 0.f, vw = 0.f;
      if constexpr (ASRC != 2) {
        if (kcol < K) {
          float4 v = *(const float4*)&A[(size_t)ar[l] * lda + kcol];
          vx = v.x; vy = v.y; vz = v.z; vw = v.w;
        }
      } else {
        int rg = ar[l];
        const float* p = nullptr;
        if (kcol < 300)       p = S0 + (size_t)rg * 300 + kcol;
        else if (kcol < 1324) p = S1 + (size_t)rg * 1024 + (kcol - 300);
        else if (kcol < 2348) p = S2 + (size_t)rg * 1024 + (kcol - 1324);
        else if (kcol < 3372) p = S3 + (size_t)rg * 1024 + (kcol - 2348);
        if (p) { float4 v = *(const float4*)p; vx = v.x; vy = v.y; vz = v.z; vw = v.w; }
      }
      u16x4 hv, lv;
      {
        unsigned short h;
        h = f2bf(vx); hv[0] = h; lv[0] = f2bf(vx - bf2f(h));
        h = f2bf(vy); hv[1] = h; lv[1] = f2bf(vy - bf2f(h));
        h = f2bf(vz); hv[2] = h; lv[2] = f2bf(vz - bf2f(h));
        h = f2bf(vw); hv[3] = h; lv[3] = f2bf(vw - bf2f(h));
      }
      int idx = tr[l] * 64 + ((c4 * 4) ^ ((tr[l] & 7) << 3));
      *(u16x4*)&sAh[idx] = hv;
      *(u16x4*)&sAl[idx] = lv;
    }
    // ---- stage B: pre-split copy, swizzled LDS ----
#pragma unroll
    for (int l = 0; l < BC8; ++l) {
      int flat = t + l * THREADS;
      int n = flat >> 3, c8 = flat & 7;
      size_t g = (size_t)(bn * BN + n) * Kpad + k0 + c8 * 8;
      int idx = n * 64 + ((c8 * 8) ^ ((n & 7) << 3));
      *(uint4*)&sBh[idx] = *(const uint4*)&Bhi[g];
      *(uint4*)&sBl[idx] = *(const uint4*)&Blo[g];
    }
    __syncthreads();
#pragma unroll
    for (int ks = 0; ks < 2; ++ks) {
      bf16x8 ah[MR], al_[MR], bh[NR], bl[NR];
      int kk = ks * 32 + (lane >> 4) * 8;
#pragma unroll
      for (int fm = 0; fm < MR; ++fm) {
        int r = wm * BMW + fm * 16 + (lane & 15);
        int idx = r * 64 + (kk ^ ((r & 7) << 3));
        ah[fm] = *(bf16x8*)&sAh[idx];
        al_[fm] = *(bf16x8*)&sAl[idx];
      }
#pragma unroll
      for (int fn = 0; fn < NR; ++fn) {
        int r = wn * BNW + fn * 16 + (lane & 15);
        int idx = r * 64 + (kk ^ ((r & 7) << 3));
        bh[fn] = *(bf16x8*)&sBh[idx];
        bl[fn] = *(bf16x8*)&sBl[idx];
      }
#pragma unroll
      for (int fm = 0; fm < MR; ++fm)
#pragma unroll
        for (int fn = 0; fn < NR; ++fn) {
          acc[fm][fn] = __builtin_amdgcn_mfma_f32_16x16x32_bf16(ah[fm], bh[fn], acc[fm][fn], 0, 0, 0);
          acc[fm][fn] = __builtin_amdgcn_mfma_f32_16x16x32_bf16(ah[fm], bl[fn], acc[fm][fn], 0, 0, 0);
          acc[fm][fn] = __builtin_amdgcn_mfma_f32_16x16x32_bf16(al_[fm], bh[fn], acc[fm][fn], 0, 0, 0);
        }
    }
    __syncthreads();
  }
  // ---- epilogue ----
#pragma unroll
  for (int fm = 0; fm < MR; ++fm)
#pragma unroll
    for (int fn = 0; fn < NR; ++fn) {
      int col = bn * BN + wn * BNW + fn * 16 + (lane & 15);
      float bi = bias[col];
      float scale = 0.f, shift = 0.f;
      if constexpr (EPI != 0) {
        scale = gam[col] * (1.0f / sqrtf(var[col] + EPSV));
        shift = bet[col] - mu[col] * scale;
      }
#pragma unroll
      for (int r = 0; r < 4; ++r) {
        int row = bm * BM + wm * BMW + fm * 16 + (lane >> 4) * 4 + r;
        float v = acc[fm][fn][r] + bi;
        if constexpr (EPI == 0) {
          v = v > 0.f ? v : LEAKYV * v;
        } else if constexpr (EPI == 1) {
          v = v * scale + shift;
          v = v > 0.f ? v : LEAKYV * v;
        } else {
          v = v > 0.f ? v : RRELUV * v;
          v = v * scale + shift;
        }
        C[(size_t)row * ldc + col] = v;
      }
    }
}

// ---------------- final y = o @ W4 + b4 ----------------
__global__ __launch_bounds__(256) void out_y_k(const float* __restrict__ o,
                                               const float* __restrict__ W4,
                                               const float* __restrict__ b4,
                                               float* __restrict__ y, int B) {
  int w = (blockIdx.x * blockDim.x + threadIdx.x) >> 6;
  int lane = threadIdx.x & 63;
  if (w >= B) return;
  float v = o[(size_t)w * 128 + lane] * W4[lane] +
            o[(size_t)w * 128 + 64 + lane] * W4[64 + lane];
  v += __shfl_down(v, 32, 64);
  v += __shfl_down(v, 16, 64);
  v += __shfl_down(v, 8, 64);
  v += __shfl_down(v, 4, 64);
  v += __shfl_down(v, 2, 64);
  v += __shfl_down(v, 1, 64);
  if (lane == 0) y[w] = v + b4[0];
}

// ---------------------------------------------------------------------------
static inline int nblk(long long n, int t) {
  long long b = (n + t - 1) / t;
  if (b > 2048) b = 2048;
  return (int)b;
}

extern "C" void kernel_launch(void* const* d_in, const int* in_sizes, int n_in,
                              void* d_out, int out_size, void* d_ws, size_t ws_size,
                              hipStream_t stream) {
  const int*   d_index = (const int*)d_in[0];
  const int*   p_index = (const int*)d_in[1];
  const float* d_vecs  = (const float*)d_in[2];
  const float* p_emb   = (const float*)d_in[3];
  const float* d_ecfps = (const float*)d_in[4];
  const int*   d_eidx  = (const int*)d_in[5];
  const float* d_ew    = (const float*)d_in[6];
  const float* p_gos   = (const float*)d_in[7];
  const int*   p_eidx  = (const int*)d_in[8];
  const float* p_ew    = (const float*)d_in[9];
  const float* Wd = (const float*)d_in[10]; const float* bd = (const float*)d_in[11];
  const float* Wp = (const float*)d_in[12]; const float* bp = (const float*)d_in[13];
  const float* W1 = (const float*)d_in[14]; const float* b1 = (const float*)d_in[15];
  const float* g1 = (const float*)d_in[16]; const float* be1 = (const float*)d_in[17];
  const float* m1 = (const float*)d_in[18]; const float* v1 = (const float*)d_in[19];
  const float* W2 = (const float*)d_in[20]; const float* b2 = (const float*)d_in[21];
  const float* g2 = (const float*)d_in[22]; const float* be2 = (const float*)d_in[23];
  const float* m2 = (const float*)d_in[24]; const float* v2 = (const float*)d_in[25];
  const float* W3 = (const float*)d_in[26]; const float* b3 = (const float*)d_in[27];
  const float* g3 = (const float*)d_in[28]; const float* be3 = (const float*)d_in[29];
  const float* m3 = (const float*)d_in[30]; const float* v3 = (const float*)d_in[31];
  const float* W4 = (const float*)d_in[32]; const float* b4 = (const float*)d_in[33];

  const int B  = in_sizes[0];
  const int ND = in_sizes[4] / 1024;
  const int NP = in_sizes[7] / 2812;
  const int ED = in_sizes[5] / 2;
  const int EP = in_sizes[8] / 2;

  // ---- workspace carve-up ----
  char* w = (char*)d_ws;
  auto carve = [&](size_t bytes) {
    char* p = w;
    w += (bytes + 255) & ~(size_t)255;
    return p;
  };
  float* deg_d = (float*)carve((size_t)ND * 4);
  float* deg_p = (float*)carve((size_t)NP * 4);
  int* slot_d = (int*)carve((size_t)ND * 4);
  int* slot_p = (int*)carve((size_t)NP * 4);
  int* cnt_d  = (int*)carve((size_t)ND * 4);
  int* cnt_p  = (int*)carve((size_t)NP * 4);
  int* fil_d  = (int*)carve((size_t)ND * 4);
  int* fil_p  = (int*)carve((size_t)NP * 4);
  int* totals = (int*)carve(256);
  int* rs_d   = (int*)carve((size_t)ND * 4);
  int* rs_p   = (int*)carve((size_t)NP * 4);
  int* rmap_d = (int*)carve((size_t)B * 4);
  int* rmap_p = (int*)carve((size_t)B * 4);
  int* elist_d = (int*)carve((size_t)ED * 4);
  int* elist_p = (int*)carve((size_t)EP * 4);
  float* agg_d = (float*)carve((size_t)B * 1024 * 4);
  float* agg_p = (float*)carve((size_t)B * 2812 * 4);
  float* ecf_b = (float*)carve((size_t)B * 1024 * 4);
  float* gos_b = (float*)carve((size_t)B * 1024 * 4);
  float* h1    = (float*)carve((size_t)B * 1024 * 4);
  float* o3    = (float*)carve((size_t)B * 128 * 4);
  // split/transposed weights [N][Kpad] bf16
  unsigned short* Wdt_h = (unsigned short*)carve((size_t)1024 * 1024 * 2);
  unsigned short* Wdt_l = (unsigned short*)carve((size_t)1024 * 1024 * 2);
  unsigned short* Wpt_h = (unsigned short*)carve((size_t)1024 * 2816 * 2);
  unsigned short* Wpt_l = (unsigned short*)carve((size_t)1024 * 2816 * 2);
  unsigned short* W1t_h = (unsigned short*)carve((size_t)1024 * 3392 * 2);
  unsigned short* W1t_l = (unsigned short*)carve((size_t)1024 * 3392 * 2);
  unsigned short* W2t_h = (unsigned short*)carve((size_t)512 * 1024 * 2);
  unsigned short* W2t_l = (unsigned short*)carve((size_t)512 * 1024 * 2);
  unsigned short* W3t_h = (unsigned short*)carve((size_t)128 * 512 * 2);
  unsigned short* W3t_l = (unsigned short*)carve((size_t)128 * 512 * 2);
  (void)ws_size; (void)n_in; (void)out_size;

  float* y_out   = (float*)d_out;
  float* feature = (float*)d_out + B;  // [B,512]

  // ---- init ----
  int n_deg  = (int)(((char*)slot_d - (char*)deg_d) / 4);
  int n_slot = (int)(((char*)cnt_d - (char*)slot_d) / 4);
  int n_zero = (int)(((char*)rs_d - (char*)cnt_d) / 4);
  fill_f32_k<<<nblk(n_deg, 256), 256, 0, stream>>>(deg_d, 2.0f, n_deg);
  fill_i32_k<<<nblk(n_slot, 256), 256, 0, stream>>>(slot_d, -1, n_slot);
  fill_i32_k<<<nblk(n_zero, 256), 256, 0, stream>>>(cnt_d, 0, n_zero);

  // ---- weight split/transpose (independent of graph prep) ----
  wsplit_k<<<dim3(32, 32), 256, 0, stream>>>(Wd, 1024, 1024, 1024, Wdt_h, Wdt_l);
  wsplit_k<<<dim3(32, 88), 256, 0, stream>>>(Wp, 2812, 1024, 2816, Wpt_h, Wpt_l);
  wsplit_k<<<dim3(32, 106), 256, 0, stream>>>(W1, 3372, 1024, 3392, W1t_h, W1t_l);
  wsplit_k<<<dim3(16, 32), 256, 0, stream>>>(W2, 1024, 512, 1024, W2t_h, W2t_l);
  wsplit_k<<<dim3(4, 16), 256, 0, stream>>>(W3, 512, 128, 512, W3t_h, W3t_l);

  // ---- degrees -> dinv ----
  deg_accum_k<<<nblk(ED, 256), 256, 0, stream>>>(d_eidx + ED, d_ew, deg_d, ED);
  deg_accum_k<<<nblk(EP, 256), 256, 0, stream>>>(p_eidx + EP, p_ew, deg_p, EP);
  dinv_k<<<nblk(ND, 256), 256, 0, stream>>>(deg_d, ND);
  dinv_k<<<nblk(NP, 256), 256, 0, stream>>>(deg_p, NP);

  // ---- needed-node slots, compact per-dst edge lists ----
  slot_k<<<(B + 255) / 256, 256, 0, stream>>>(d_index, slot_d, B);
  slot_k<<<(B + 255) / 256, 256, 0, stream>>>(p_index, slot_p, B);
  count_k<<<nblk(ED, 256), 256, 0, stream>>>(d_eidx + ED, slot_d, cnt_d, ED);
  count_k<<<nblk(EP, 256), 256, 0, stream>>>(p_eidx + EP, slot_p, cnt_p, EP);
  alloc_k<<<nblk(ND, 256), 256, 0, stream>>>(cnt_d, rs_d, totals + 0, ND);
  alloc_k<<<nblk(NP, 256), 256, 0, stream>>>(cnt_p, rs_p, totals + 1, NP);
  fill_edges_k<<<nblk(ED, 256), 256, 0, stream>>>(d_eidx + ED, slot_d, rs_d, fil_d, elist_d, ED);
  fill_edges_k<<<nblk(EP, 256), 256, 0, stream>>>(p_eidx + EP, slot_p, rs_p, fil_p, elist_p, EP);
  rowmap_k<<<(B + 255) / 256, 256, 0, stream>>>(d_index, slot_d, rmap_d, B);
  rowmap_k<<<(B + 255) / 256, 256, 0, stream>>>(p_index, slot_p, rmap_p, B);

  // ---- input-space aggregation ----
  gcn_agg_k<1024><<<B, 256, 0, stream>>>(d_ecfps, d_index, slot_d, deg_d,
                                         d_eidx, d_ew, elist_d, rs_d, cnt_d, agg_d);
  gcn_agg_k<2812><<<B, 256, 0, stream>>>(p_gos, p_index, slot_p, deg_p,
                                         p_eidx, p_ew, elist_p, rs_p, cnt_p, agg_p);

  // ---- MFMA GEMM stack ----
  // G1: ecf_b = leaky(agg_d[rowmap] @ Wd + bd)      [4096,1024] K=1024
  mgemm_k<128, 128, 2, 4, 1, 0><<<dim3(8, 32), 512, 0, stream>>>(
      agg_d, 1024, Wdt_h, Wdt_l, 1024, ecf_b, 1024, 1024, rmap_d,
      nullptr, nullptr, nullptr, nullptr, bd, nullptr, nullptr, nullptr, nullptr);
  // G2: gos_b = leaky(agg_p[rowmap] @ Wp + bp)      [4096,1024] K=2812
  mgemm_k<128, 128, 2, 4, 1, 0><<<dim3(8, 32), 512, 0, stream>>>(
      agg_p, 2812, Wpt_h, Wpt_l, 2816, gos_b, 1024, 2812, rmap_p,
      nullptr, nullptr, nullptr, nullptr, bp, nullptr, nullptr, nullptr, nullptr);
  // G3: h1 = leaky(bn1(concat @ W1 + b1))           [4096,1024] K=3372
  mgemm_k<128, 128, 2, 4, 2, 1><<<dim3(8, 32), 512, 0, stream>>>(
      nullptr, 0, W1t_h, W1t_l, 3392, h1, 1024, 3372, nullptr,
      d_vecs, p_emb, ecf_b, gos_b, b1, g1, be1, m1, v1);
  // G4: feature = leaky(bn2(h1 @ W2 + b2))          [4096,512] K=1024 -> d_out
  mgemm_k<64, 64, 2, 2, 0, 1><<<dim3(8, 64), 256, 0, stream>>>(
      h1, 1024, W2t_h, W2t_l, 1024, feature, 512, 1024, nullptr,
      nullptr, nullptr, nullptr, nullptr, b2, g2, be2, m2, v2);
  // G5: o3 = bn3(rrelu(feature @ W3 + b3))          [4096,128] K=512
  mgemm_k<64, 64, 2, 2, 0, 2><<<dim3(2, 64), 256, 0, stream>>>(
      feature, 512, W3t_h, W3t_l, 512, o3, 128, 512, nullptr,
      nullptr, nullptr, nullptr, nullptr, b3, g3, be3, m3, v3);
  // y = o3 @ W4 + b4
  out_y_k<<<(B * 64 + 255) / 256, 256, 0, stream>>>(o3, W4, b4, y_out, B);
}

// Round 3
// 1348.246 us; speedup vs baseline: 1.8253x; 1.0511x over previous
//
#include <hip/hip_runtime.h>

// ---------------------------------------------------------------------------
// FC — GCN aggregate-before-matmul + pre-split bf16(hi,lo) MFMA GEMM stack.
// out = concat(y[4096], feature[4096*512]) f32.
// ---------------------------------------------------------------------------

#define EPSV 1e-5f
#define LEAKYV 0.01f
#define RRELUV 0.22916666666666666f  // (1/8 + 1/3)/2

typedef __bf16 bf16x8 __attribute__((ext_vector_type(8)));
typedef float f32x4 __attribute__((ext_vector_type(4)));

__device__ __forceinline__ unsigned short f2bf(float x) {  // RNE to bf16
  unsigned u = __builtin_bit_cast(unsigned, x);
  u = (u + 0x7FFFu + ((u >> 16) & 1u)) >> 16;
  return (unsigned short)u;
}
__device__ __forceinline__ float bf2f(unsigned short h) {
  unsigned u = ((unsigned)h) << 16;
  return __builtin_bit_cast(float, u);
}

// ---------------- tiny utility kernels ----------------
__global__ void fill_f32_k(float* __restrict__ p, float v, int n) {
  int i = blockIdx.x * blockDim.x + threadIdx.x;
  int st = gridDim.x * blockDim.x;
  for (; i < n; i += st) p[i] = v;
}
__global__ void fill_i32_k(int* __restrict__ p, int v, int n) {
  int i = blockIdx.x * blockDim.x + threadIdx.x;
  int st = gridDim.x * blockDim.x;
  for (; i < n; i += st) p[i] = v;
}
__global__ void deg_accum_k(const int* __restrict__ dst, const float* __restrict__ w,
                            float* __restrict__ deg, int E) {
  int i = blockIdx.x * blockDim.x + threadIdx.x;
  int st = gridDim.x * blockDim.x;
  for (; i < E; i += st) atomicAdd(&deg[dst[i]], w[i]);
}
__global__ void dinv_k(float* __restrict__ deg, int n) {
  int i = blockIdx.x * blockDim.x + threadIdx.x;
  int st = gridDim.x * blockDim.x;
  for (; i < n; i += st) deg[i] = 1.0f / sqrtf(deg[i]);
}
__global__ void slot_k(const int* __restrict__ idx, int* __restrict__ slot, int B) {
  int i = blockIdx.x * blockDim.x + threadIdx.x;
  if (i < B) atomicCAS(&slot[idx[i]], -1, i);
}
__global__ void count_k(const int* __restrict__ dst, const int* __restrict__ slot,
                        int* __restrict__ cnt, int E) {
  int i = blockIdx.x * blockDim.x + threadIdx.x;
  int st = gridDim.x * blockDim.x;
  for (; i < E; i += st) { int d = dst[i]; if (slot[d] >= 0) atomicAdd(&cnt[d], 1); }
}
__global__ void alloc_k(const int* __restrict__ cnt, int* __restrict__ rowstart,
                        int* __restrict__ total, int n) {
  int i = blockIdx.x * blockDim.x + threadIdx.x;
  int st = gridDim.x * blockDim.x;
  for (; i < n; i += st) { int c = cnt[i]; if (c > 0) rowstart[i] = atomicAdd(total, c); }
}
// filtered edges -> compact (src, coef) arrays, segmented per dst
__global__ void fill_edges_k(const int* __restrict__ src, const int* __restrict__ dst,
                             const float* __restrict__ ew, const float* __restrict__ dinv,
                             const int* __restrict__ slot, const int* __restrict__ rowstart,
                             int* __restrict__ fil, int* __restrict__ srcs,
                             float* __restrict__ cfs, int E) {
  int i = blockIdx.x * blockDim.x + threadIdx.x;
  int st = gridDim.x * blockDim.x;
  for (; i < E; i += st) {
    int d = dst[i];
    if (slot[d] >= 0) {
      int p = rowstart[d] + atomicAdd(&fil[d], 1);
      int s = src[i];
      srcs[p] = s;
      cfs[p] = ew[i] * dinv[s] * dinv[d];
    }
  }
}
__global__ void rowmap_k(const int* __restrict__ idx, const int* __restrict__ slot,
                         int* __restrict__ rmap, int B) {
  int i = blockIdx.x * blockDim.x + threadIdx.x;
  if (i < B) rmap[i] = slot[idx[i]];
}

// ---------------- GCN aggregation (segmented, compact meta, split-bf16 out) --
template <int ROWLEN, int KPAD, int SEGV4>
__global__ __launch_bounds__(128) void gcn_agg2_k(
    const float* __restrict__ x, const int* __restrict__ bidx,
    const int* __restrict__ slot, const float* __restrict__ dinv,
    const int* __restrict__ srcs, const float* __restrict__ cfs,
    const int* __restrict__ rowstart, const int* __restrict__ cnt,
    unsigned short* __restrict__ aggH, unsigned short* __restrict__ aggL) {
  constexpr int NV4 = ROWLEN / 4;
  constexpr int KPV4 = KPAD / 4;
  int t = threadIdx.x;
  if (t >= SEGV4) return;
  int g4 = blockIdx.y * SEGV4 + t;
  if (g4 >= KPV4) return;
  int i = blockIdx.x;
  int node = bidx[i];
  if (slot[node] != i) return;

  ushort4 zh = {0, 0, 0, 0};
  if (g4 >= NV4) {  // zero-pad columns
    *(ushort4*)&aggH[(size_t)i * KPAD + g4 * 4] = zh;
    *(ushort4*)&aggL[(size_t)i * KPAD + g4 * 4] = zh;
    return;
  }
  float dn = dinv[node];
  float cs = 2.0f * dn * dn;
  float4 v = *(const float4*)&x[(size_t)node * ROWLEN + g4 * 4];
  float ax = cs * v.x, ay = cs * v.y, az = cs * v.z, aw = cs * v.w;

  int j = rowstart[node];
  int end = j + cnt[node];
  for (; j + 4 <= end; j += 4) {
    int s0 = srcs[j], s1 = srcs[j + 1], s2 = srcs[j + 2], s3 = srcs[j + 3];
    float c0 = cfs[j], c1 = cfs[j + 1], c2 = cfs[j + 2], c3 = cfs[j + 3];
    float4 v0 = *(const float4*)&x[(size_t)s0 * ROWLEN + g4 * 4];
    float4 v1 = *(const float4*)&x[(size_t)s1 * ROWLEN + g4 * 4];
    float4 v2 = *(const float4*)&x[(size_t)s2 * ROWLEN + g4 * 4];
    float4 v3 = *(const float4*)&x[(size_t)s3 * ROWLEN + g4 * 4];
    ax += c0 * v0.x + c1 * v1.x + c2 * v2.x + c3 * v3.x;
    ay += c0 * v0.y + c1 * v1.y + c2 * v2.y + c3 * v3.y;
    az += c0 * v0.z + c1 * v1.z + c2 * v2.z + c3 * v3.z;
    aw += c0 * v0.w + c1 * v1.w + c2 * v2.w + c3 * v3.w;
  }
  for (; j < end; ++j) {
    int s0 = srcs[j];
    float c0 = cfs[j];
    float4 v0 = *(const float4*)&x[(size_t)s0 * ROWLEN + g4 * 4];
    ax += c0 * v0.x; ay += c0 * v0.y; az += c0 * v0.z; aw += c0 * v0.w;
  }
  ushort4 h, l;
  h.x = f2bf(ax); l.x = f2bf(ax - bf2f(h.x));
  h.y = f2bf(ay); l.y = f2bf(ay - bf2f(h.y));
  h.z = f2bf(az); l.z = f2bf(az - bf2f(h.z));
  h.w = f2bf(aw); l.w = f2bf(aw - bf2f(h.w));
  *(ushort4*)&aggH[(size_t)i * KPAD + g4 * 4] = h;
  *(ushort4*)&aggL[(size_t)i * KPAD + g4 * 4] = l;
}

// ---------------- d_vecs | p_emb -> concat cols [0,1324) + pad [3372,3392) ---
__global__ void dvp_split_k(const float* __restrict__ dv, const float* __restrict__ pe,
                            unsigned short* __restrict__ catH,
                            unsigned short* __restrict__ catL, int B) {
  int id = blockIdx.x * blockDim.x + threadIdx.x;
  int st = gridDim.x * blockDim.x;
  int ntask = B * 336;  // 75 dv + 256 pe + 5 pad float4s per row
  for (; id < ntask; id += st) {
    int r = id / 336, j = id - r * 336;
    float4 v = {0.f, 0.f, 0.f, 0.f};
    int col4;
    if (j < 75) { v = *(const float4*)&dv[(size_t)r * 300 + j * 4]; col4 = j; }
    else if (j < 331) { v = *(const float4*)&pe[(size_t)r * 1024 + (j - 75) * 4]; col4 = j; }
    else col4 = 843 + (j - 331);
    ushort4 h, l;
    h.x = f2bf(v.x); l.x = f2bf(v.x - bf2f(h.x));
    h.y = f2bf(v.y); l.y = f2bf(v.y - bf2f(h.y));
    h.z = f2bf(v.z); l.z = f2bf(v.z - bf2f(h.z));
    h.w = f2bf(v.w); l.w = f2bf(v.w - bf2f(h.w));
    *(ushort4*)&catH[(size_t)r * 3392 + col4 * 4] = h;
    *(ushort4*)&catL[(size_t)r * 3392 + col4 * 4] = l;
  }
}

// ---------------- weight transpose + bf16 split: W[K][N] -> hi/lo [N][Kpad] --
__global__ __launch_bounds__(256) void wsplit_k(const float* __restrict__ W, int K, int N,
                                                int Kpad, unsigned short* __restrict__ hi,
                                                unsigned short* __restrict__ lo) {
  __shared__ float tile[32][33];
  int tx = threadIdx.x & 31, ty = threadIdx.x >> 5;
  int n0 = blockIdx.x * 32, k0 = blockIdx.y * 32;
#pragma unroll
  for (int i = 0; i < 4; ++i) {
    int k = k0 + ty + i * 8, n = n0 + tx;
    tile[ty + i * 8][tx] = (k < K && n < N) ? W[(size_t)k * N + n] : 0.f;
  }
  __syncthreads();
#pragma unroll
  for (int i = 0; i < 4; ++i) {
    int n = n0 + ty + i * 8, k = k0 + tx;
    if (n < N && k < Kpad) {
      float v = tile[tx][ty + i * 8];
      unsigned short h = f2bf(v);
      hi[(size_t)n * Kpad + k] = h;
      lo[(size_t)n * Kpad + k] = f2bf(v - bf2f(h));
    }
  }
}

// ---------------- split-bf16 MFMA GEMM (pre-split A and B) ----------------
// C = EPI(A[M,K] @ B^T + bias); A hi/lo [M][Kpad], B hi/lo [N][Kpad].
// BM=BN=128, BK=64, 256 thr (4 waves, wave-tile 64x64).
// ASRC: 0 direct rows, 1 rows via rowmap.
// EPI:  0 leaky, 1 leaky(bn(.)), 2 bn(rrelu(.)).
// OUTM: 0 f32 only, 1 split only, 2 both.
template <int ASRC, int EPI, int OUTM>
__global__ __launch_bounds__(256) void mgemm_k(
    const unsigned short* __restrict__ Ahi, const unsigned short* __restrict__ Alo,
    const unsigned short* __restrict__ Bhi, const unsigned short* __restrict__ Blo,
    int Kpad, int nk, float* __restrict__ Cf, int ldc,
    unsigned short* __restrict__ CH, unsigned short* __restrict__ CL, int ldcs, int coff,
    const int* __restrict__ rowmap, const float* __restrict__ bias,
    const float* __restrict__ gam, const float* __restrict__ bet,
    const float* __restrict__ mu, const float* __restrict__ var) {
  __shared__ __attribute__((aligned(16))) unsigned short sAh[128 * 64];
  __shared__ __attribute__((aligned(16))) unsigned short sAl[128 * 64];
  __shared__ __attribute__((aligned(16))) unsigned short sBh[128 * 64];
  __shared__ __attribute__((aligned(16))) unsigned short sBl[128 * 64];

  int t = threadIdx.x;
  int lane = t & 63, wid = t >> 6;
  int wm = wid >> 1, wn = wid & 1;
  int bm = blockIdx.y, bn = blockIdx.x;

  // staging rows (4 chunks of 8 bf16 per thread per buffer)
  int arow[4], brow[4], c8v[4];
#pragma unroll
  for (int l = 0; l < 4; ++l) {
    int flat = t + l * 256;
    int row = flat >> 3;
    c8v[l] = flat & 7;
    int rg = bm * 128 + row;
    if constexpr (ASRC == 1) arow[l] = rowmap[rg];
    else arow[l] = rg;
    brow[l] = bn * 128 + row;
  }

  f32x4 acc[4][4];
#pragma unroll
  for (int i = 0; i < 4; ++i)
#pragma unroll
    for (int j = 0; j < 4; ++j) acc[i][j] = (f32x4){0.f, 0.f, 0.f, 0.f};

  for (int kt = 0; kt < nk; ++kt) {
    int k0 = kt * 64;
#pragma unroll
    for (int l = 0; l < 4; ++l) {
      int flat = t + l * 256;
      int row = flat >> 3, c8 = c8v[l];
      size_t ga = (size_t)arow[l] * Kpad + k0 + c8 * 8;
      size_t gb = (size_t)brow[l] * Kpad + k0 + c8 * 8;
      uint4 vah = *(const uint4*)&Ahi[ga];
      uint4 val = *(const uint4*)&Alo[ga];
      uint4 vbh = *(const uint4*)&Bhi[gb];
      uint4 vbl = *(const uint4*)&Blo[gb];
      int idx = row * 64 + ((c8 * 8) ^ ((row & 7) << 3));
      *(uint4*)&sAh[idx] = vah;
      *(uint4*)&sAl[idx] = val;
      *(uint4*)&sBh[idx] = vbh;
      *(uint4*)&sBl[idx] = vbl;
    }
    __syncthreads();
#pragma unroll
    for (int ks = 0; ks < 2; ++ks) {
      int kk = ks * 32 + (lane >> 4) * 8;
      bf16x8 bh[4], bl[4];
#pragma unroll
      for (int fn = 0; fn < 4; ++fn) {
        int r = wn * 64 + fn * 16 + (lane & 15);
        int idx = r * 64 + (kk ^ ((r & 7) << 3));
        bh[fn] = *(bf16x8*)&sBh[idx];
        bl[fn] = *(bf16x8*)&sBl[idx];
      }
#pragma unroll
      for (int fm = 0; fm < 4; ++fm) {
        int r = wm * 64 + fm * 16 + (lane & 15);
        int idx = r * 64 + (kk ^ ((r & 7) << 3));
        bf16x8 ah = *(bf16x8*)&sAh[idx];
        bf16x8 al = *(bf16x8*)&sAl[idx];
#pragma unroll
        for (int fn = 0; fn < 4; ++fn) {
          acc[fm][fn] = __builtin_amdgcn_mfma_f32_16x16x32_bf16(ah, bh[fn], acc[fm][fn], 0, 0, 0);
          acc[fm][fn] = __builtin_amdgcn_mfma_f32_16x16x32_bf16(ah, bl[fn], acc[fm][fn], 0, 0, 0);
          acc[fm][fn] = __builtin_amdgcn_mfma_f32_16x16x32_bf16(al, bh[fn], acc[fm][fn], 0, 0, 0);
        }
      }
    }
    __syncthreads();
  }
  // ---- epilogue ----
#pragma unroll
  for (int fm = 0; fm < 4; ++fm)
#pragma unroll
    for (int fn = 0; fn < 4; ++fn) {
      int col = bn * 128 + wn * 64 + fn * 16 + (lane & 15);
      float bi = bias[col];
      float scale = 0.f, shift = 0.f;
      if constexpr (EPI != 0) {
        scale = gam[col] * (1.0f / sqrtf(var[col] + EPSV));
        shift = bet[col] - mu[col] * scale;
      }
#pragma unroll
      for (int r = 0; r < 4; ++r) {
        int row = bm * 128 + wm * 64 + fm * 16 + (lane >> 4) * 4 + r;
        float v = acc[fm][fn][r] + bi;
        if constexpr (EPI == 0) {
          v = v > 0.f ? v : LEAKYV * v;
        } else if constexpr (EPI == 1) {
          v = v * scale + shift;
          v = v > 0.f ? v : LEAKYV * v;
        } else {
          v = v > 0.f ? v : RRELUV * v;
          v = v * scale + shift;
        }
        if constexpr (OUTM != 1) Cf[(size_t)row * ldc + col] = v;
        if constexpr (OUTM != 0) {
          unsigned short h = f2bf(v);
          CH[(size_t)row * ldcs + coff + col] = h;
          CL[(size_t)row * ldcs + coff + col] = f2bf(v - bf2f(h));
        }
      }
    }
}

// ---------------- final y = o @ W4 + b4 ----------------
__global__ __launch_bounds__(256) void out_y_k(const float* __restrict__ o,
                                               const float* __restrict__ W4,
                                               const float* __restrict__ b4,
                                               float* __restrict__ y, int B) {
  int w = (blockIdx.x * blockDim.x + threadIdx.x) >> 6;
  int lane = threadIdx.x & 63;
  if (w >= B) return;
  float v = o[(size_t)w * 128 + lane] * W4[lane] +
            o[(size_t)w * 128 + 64 + lane] * W4[64 + lane];
  v += __shfl_down(v, 32, 64);
  v += __shfl_down(v, 16, 64);
  v += __shfl_down(v, 8, 64);
  v += __shfl_down(v, 4, 64);
  v += __shfl_down(v, 2, 64);
  v += __shfl_down(v, 1, 64);
  if (lane == 0) y[w] = v + b4[0];
}

// ---------------------------------------------------------------------------
static inline int nblk(long long n, int t) {
  long long b = (n + t - 1) / t;
  if (b > 2048) b = 2048;
  return (int)b;
}

extern "C" void kernel_launch(void* const* d_in, const int* in_sizes, int n_in,
                              void* d_out, int out_size, void* d_ws, size_t ws_size,
                              hipStream_t stream) {
  const int*   d_index = (const int*)d_in[0];
  const int*   p_index = (const int*)d_in[1];
  const float* d_vecs  = (const float*)d_in[2];
  const float* p_emb   = (const float*)d_in[3];
  const float* d_ecfps = (const float*)d_in[4];
  const int*   d_eidx  = (const int*)d_in[5];
  const float* d_ew    = (const float*)d_in[6];
  const float* p_gos   = (const float*)d_in[7];
  const int*   p_eidx  = (const int*)d_in[8];
  const float* p_ew    = (const float*)d_in[9];
  const float* Wd = (const float*)d_in[10]; const float* bd = (const float*)d_in[11];
  const float* Wp = (const float*)d_in[12]; const float* bp = (const float*)d_in[13];
  const float* W1 = (const float*)d_in[14]; const float* b1 = (const float*)d_in[15];
  const float* g1 = (const float*)d_in[16]; const float* be1 = (const float*)d_in[17];
  const float* m1 = (const float*)d_in[18]; const float* v1 = (const float*)d_in[19];
  const float* W2 = (const float*)d_in[20]; const float* b2 = (const float*)d_in[21];
  const float* g2 = (const float*)d_in[22]; const float* be2 = (const float*)d_in[23];
  const float* m2 = (const float*)d_in[24]; const float* v2 = (const float*)d_in[25];
  const float* W3 = (const float*)d_in[26]; const float* b3 = (const float*)d_in[27];
  const float* g3 = (const float*)d_in[28]; const float* be3 = (const float*)d_in[29];
  const float* m3 = (const float*)d_in[30]; const float* v3 = (const float*)d_in[31];
  const float* W4 = (const float*)d_in[32]; const float* b4 = (const float*)d_in[33];

  const int B  = in_sizes[0];
  const int ND = in_sizes[4] / 1024;
  const int NP = in_sizes[7] / 2812;
  const int ED = in_sizes[5] / 2;
  const int EP = in_sizes[8] / 2;

  // ---- workspace carve-up ----
  char* w = (char*)d_ws;
  auto carve = [&](size_t bytes) {
    char* p = w;
    w += (bytes + 255) & ~(size_t)255;
    return p;
  };
  float* deg_d = (float*)carve((size_t)ND * 4);
  float* deg_p = (float*)carve((size_t)NP * 4);
  int* slot_d = (int*)carve((size_t)ND * 4);
  int* slot_p = (int*)carve((size_t)NP * 4);
  int* cnt_d  = (int*)carve((size_t)ND * 4);
  int* cnt_p  = (int*)carve((size_t)NP * 4);
  int* fil_d  = (int*)carve((size_t)ND * 4);
  int* fil_p  = (int*)carve((size_t)NP * 4);
  int* totals = (int*)carve(256);
  int* rs_d   = (int*)carve((size_t)ND * 4);
  int* rs_p   = (int*)carve((size_t)NP * 4);
  int* rmap_d = (int*)carve((size_t)B * 4);
  int* rmap_p = (int*)carve((size_t)B * 4);
  int* srcs_d = (int*)carve((size_t)ED * 4);
  float* cfs_d = (float*)carve((size_t)ED * 4);
  int* srcs_p = (int*)carve((size_t)EP * 4);
  float* cfs_p = (float*)carve((size_t)EP * 4);
  unsigned short* aggdH = (unsigned short*)carve((size_t)B * 1024 * 2);
  unsigned short* aggdL = (unsigned short*)carve((size_t)B * 1024 * 2);
  unsigned short* aggpH = (unsigned short*)carve((size_t)B * 2816 * 2);
  unsigned short* aggpL = (unsigned short*)carve((size_t)B * 2816 * 2);
  unsigned short* catH  = (unsigned short*)carve((size_t)B * 3392 * 2);
  unsigned short* catL  = (unsigned short*)carve((size_t)B * 3392 * 2);
  unsigned short* h1H   = (unsigned short*)carve((size_t)B * 1024 * 2);
  unsigned short* h1L   = (unsigned short*)carve((size_t)B * 1024 * 2);
  unsigned short* ftH   = (unsigned short*)carve((size_t)B * 512 * 2);
  unsigned short* ftL   = (unsigned short*)carve((size_t)B * 512 * 2);
  float* o3 = (float*)carve((size_t)B * 128 * 4);
  unsigned short* Wdt_h = (unsigned short*)carve((size_t)1024 * 1024 * 2);
  unsigned short* Wdt_l = (unsigned short*)carve((size_t)1024 * 1024 * 2);
  unsigned short* Wpt_h = (unsigned short*)carve((size_t)1024 * 2816 * 2);
  unsigned short* Wpt_l = (unsigned short*)carve((size_t)1024 * 2816 * 2);
  unsigned short* W1t_h = (unsigned short*)carve((size_t)1024 * 3392 * 2);
  unsigned short* W1t_l = (unsigned short*)carve((size_t)1024 * 3392 * 2);
  unsigned short* W2t_h = (unsigned short*)carve((size_t)512 * 1024 * 2);
  unsigned short* W2t_l = (unsigned short*)carve((size_t)512 * 1024 * 2);
  unsigned short* W3t_h = (unsigned short*)carve((size_t)128 * 512 * 2);
  unsigned short* W3t_l = (unsigned short*)carve((size_t)128 * 512 * 2);
  (void)ws_size; (void)n_in; (void)out_size;

  float* y_out   = (float*)d_out;
  float* feature = (float*)d_out + B;  // [B,512]

  // ---- init ----
  int n_deg  = (int)(((char*)slot_d - (char*)deg_d) / 4);
  int n_slot = (int)(((char*)cnt_d - (char*)slot_d) / 4);
  int n_zero = (int)(((char*)rs_d - (char*)cnt_d) / 4);
  fill_f32_k<<<nblk(n_deg, 256), 256, 0, stream>>>(deg_d, 2.0f, n_deg);
  fill_i32_k<<<nblk(n_slot, 256), 256, 0, stream>>>(slot_d, -1, n_slot);
  fill_i32_k<<<nblk(n_zero, 256), 256, 0, stream>>>(cnt_d, 0, n_zero);

  // ---- weight split/transpose + dvecs/pemb split (independent work first) --
  wsplit_k<<<dim3(32, 32), 256, 0, stream>>>(Wd, 1024, 1024, 1024, Wdt_h, Wdt_l);
  wsplit_k<<<dim3(32, 88), 256, 0, stream>>>(Wp, 2812, 1024, 2816, Wpt_h, Wpt_l);
  wsplit_k<<<dim3(32, 106), 256, 0, stream>>>(W1, 3372, 1024, 3392, W1t_h, W1t_l);
  wsplit_k<<<dim3(16, 32), 256, 0, stream>>>(W2, 1024, 512, 1024, W2t_h, W2t_l);
  wsplit_k<<<dim3(4, 16), 256, 0, stream>>>(W3, 512, 128, 512, W3t_h, W3t_l);
  dvp_split_k<<<2048, 256, 0, stream>>>(d_vecs, p_emb, catH, catL, B);

  // ---- degrees -> dinv ----
  deg_accum_k<<<nblk(ED, 256), 256, 0, stream>>>(d_eidx + ED, d_ew, deg_d, ED);
  deg_accum_k<<<nblk(EP, 256), 256, 0, stream>>>(p_eidx + EP, p_ew, deg_p, EP);
  dinv_k<<<nblk(ND, 256), 256, 0, stream>>>(deg_d, ND);
  dinv_k<<<nblk(NP, 256), 256, 0, stream>>>(deg_p, NP);

  // ---- needed-node slots, compact per-dst (src,coef) lists ----
  slot_k<<<(B + 255) / 256, 256, 0, stream>>>(d_index, slot_d, B);
  slot_k<<<(B + 255) / 256, 256, 0, stream>>>(p_index, slot_p, B);
  count_k<<<nblk(ED, 256), 256, 0, stream>>>(d_eidx + ED, slot_d, cnt_d, ED);
  count_k<<<nblk(EP, 256), 256, 0, stream>>>(p_eidx + EP, slot_p, cnt_p, EP);
  alloc_k<<<nblk(ND, 256), 256, 0, stream>>>(cnt_d, rs_d, totals + 0, ND);
  alloc_k<<<nblk(NP, 256), 256, 0, stream>>>(cnt_p, rs_p, totals + 1, NP);
  fill_edges_k<<<nblk(ED, 256), 256, 0, stream>>>(d_eidx, d_eidx + ED, d_ew, deg_d,
                                                  slot_d, rs_d, fil_d, srcs_d, cfs_d, ED);
  fill_edges_k<<<nblk(EP, 256), 256, 0, stream>>>(p_eidx, p_eidx + EP, p_ew, deg_p,
                                                  slot_p, rs_p, fil_p, srcs_p, cfs_p, EP);
  rowmap_k<<<(B + 255) / 256, 256, 0, stream>>>(d_index, slot_d, rmap_d, B);
  rowmap_k<<<(B + 255) / 256, 256, 0, stream>>>(p_index, slot_p, rmap_p, B);

  // ---- segmented aggregation -> split-bf16 agg buffers ----
  gcn_agg2_k<1024, 1024, 128><<<dim3(B, 2), 128, 0, stream>>>(
      d_ecfps, d_index, slot_d, deg_d, srcs_d, cfs_d, rs_d, cnt_d, aggdH, aggdL);
  gcn_agg2_k<2812, 2816, 118><<<dim3(B, 6), 128, 0, stream>>>(
      p_gos, p_index, slot_p, deg_p, srcs_p, cfs_p, rs_p, cnt_p, aggpH, aggpL);

  // ---- MFMA GEMM stack ----
  // G1: cat[:,1324:2348] = leaky(agg_d[rowmap] @ Wd + bd)   K=1024
  mgemm_k<1, 0, 1><<<dim3(8, 32), 256, 0, stream>>>(
      aggdH, aggdL, Wdt_h, Wdt_l, 1024, 16, nullptr, 0, catH, catL, 3392, 1324,
      rmap_d, bd, nullptr, nullptr, nullptr, nullptr);
  // G2: cat[:,2348:3372] = leaky(agg_p[rowmap] @ Wp + bp)   K=2816
  mgemm_k<1, 0, 1><<<dim3(8, 32), 256, 0, stream>>>(
      aggpH, aggpL, Wpt_h, Wpt_l, 2816, 44, nullptr, 0, catH, catL, 3392, 2348,
      rmap_p, bp, nullptr, nullptr, nullptr, nullptr);
  // G3: h1 = leaky(bn1(cat @ W1 + b1))                      K=3392
  mgemm_k<0, 1, 1><<<dim3(8, 32), 256, 0, stream>>>(
      catH, catL, W1t_h, W1t_l, 3392, 53, nullptr, 0, h1H, h1L, 1024, 0,
      nullptr, b1, g1, be1, m1, v1);
  // G4: feature = leaky(bn2(h1 @ W2 + b2))  -> d_out f32 + split   K=1024
  mgemm_k<0, 1, 2><<<dim3(4, 32), 256, 0, stream>>>(
      h1H, h1L, W2t_h, W2t_l, 1024, 16, feature, 512, ftH, ftL, 512, 0,
      nullptr, b2, g2, be2, m2, v2);
  // G5: o3 = bn3(rrelu(feature @ W3 + b3))                  K=512
  mgemm_k<0, 2, 0><<<dim3(1, 32), 256, 0, stream>>>(
      ftH, ftL, W3t_h, W3t_l, 512, 8, o3, 128, nullptr, nullptr, 0, 0,
      nullptr, b3, g3, be3, m3, v3);
  // y = o3 @ W4 + b4
  out_y_k<<<(B * 64 + 255) / 256, 256, 0, stream>>>(o3, W4, b4, y_out, B);
}